// Round 12
// baseline (185.517 us; speedup 1.0000x reference)
//
#include <hip/hip_runtime.h>
#include <hip/hip_bf16.h>

// Problem constants (f32 in / f32 out — established R1/R2).
constexpr int B_ = 2, S_ = 2048, D_ = 1024, H_ = 16, KVH_ = 4, HD_ = 64;

typedef __attribute__((ext_vector_type(8))) short short8;
typedef __attribute__((ext_vector_type(4))) float f32x4;
typedef __attribute__((ext_vector_type(16))) float f32x16;

// f32 -> bf16 bits, round-to-nearest-even (finite inputs).
__device__ inline short f2b(float x) {
  unsigned u = __float_as_uint(x);
  return (short)((u + 0x7fffu + ((u >> 16) & 1u)) >> 16);
}
// pack two f32 -> (bf16,bf16) u32, lo in low half (v_cvt_pk_bf16_f32).
__device__ inline unsigned pkbf2(float lo, float hi) {
  __hip_bfloat162 h = __float22bfloat162_rn(float2{lo, hi});
  return *(unsigned*)&h;
}

// Async global->LDS, 16B per lane. LDS dest = wave-uniform base + lane*16.
__device__ inline void async16(void* lds, const void* g) {
  __builtin_amdgcn_global_load_lds(
      (const __attribute__((address_space(1))) unsigned int*)g,
      (__attribute__((address_space(3))) unsigned int*)lds, 16, 0, 0);
}

// GEMM operand layouts (fragment-packed in GLOBAL memory):
//  A (M x K):  off = ((row>>6)*(K/32) + (k>>5))*2048
//                    + ((row>>4)&3)*512 + (((k>>3)&3)*16 + (row&15))*8 + (k&7)
//  B (N x K):  off = ((col>>7)*(K/32) + (k>>5))*4096
//                    + ((col>>4)&7)*512 + (((k>>3)&3)*16 + (col&15))*8 + (k&7)
// Staging is a linear 4/8 KB chunk per (block,kstep) -> async16 dest legal;
// LDS fragment reads are base + lane*16B -> bank-conflict-free.

// Merged prepass: blocks [0,4096) cast x f32->bf16 into fragment-packed
// xbF; [4096,5120) transpose weights into fragment-packed wtF/wotF.
__global__ __launch_bounds__(256) void prep_kernel(
    const float* __restrict__ x, short* __restrict__ xb,
    const float* __restrict__ wq, const float* __restrict__ wk,
    const float* __restrict__ wv, const float* __restrict__ wo,
    short* __restrict__ wt, short* __restrict__ wot) {
  __shared__ short ts[64][66];
  const int tid = threadIdx.x;
  if (blockIdx.x < 4096) {
    const int idx = (blockIdx.x * 256 + tid) * 4;
    float4 v = *(const float4*)(x + idx);
    short4 o;
    o.x = f2b(v.x); o.y = f2b(v.y); o.z = f2b(v.z); o.w = f2b(v.w);
    const int row = idx >> 10, k = idx & 1023;
    const int rb = row >> 6, w16 = (row >> 4) & 3, li = row & 15;
    const int kb = k >> 5, grp = (k >> 3) & 3, e0 = k & 7;  // e0 in {0,4}
    *(short4*)(xb + ((size_t)(rb * 32 + kb)) * 2048 + w16 * 512 +
               (grp * 16 + li) * 8 + e0) = o;
    return;
  }
  const int bid = blockIdx.x - 4096;
  const int z = bid >> 8, bi = (bid >> 4) & 15, bj = bid & 15;
  const float* W;
  short* dst;
  int N, colbase;
  if (z == 0)      { W = wq; dst = wt;  N = 1024; colbase = 0; }
  else if (z == 1) { W = wo; dst = wot; N = 1024; colbase = 0; }
  else if (z == 2) { W = wk; dst = wt;  N = 256;  colbase = 1024; }
  else             { W = wv; dst = wt;  N = 256;  colbase = 1280; }
  if (bj * 64 >= N) return;
#pragma unroll
  for (int i = 0; i < 16; ++i) {
    int idx = tid + i * 256;
    int r = idx >> 6, c = idx & 63;
    ts[r][c] = f2b(W[(size_t)(bi * 64 + r) * N + bj * 64 + c]);
  }
  __syncthreads();
#pragma unroll
  for (int i = 0; i < 16; ++i) {
    int idx = tid + i * 256;
    int cc = idx >> 6, rr = idx & 63;
    const int colg = colbase + bj * 64 + cc;
    const int k = bi * 64 + rr;
    const int cb2 = colg >> 7, nt2 = (colg >> 4) & 7, li2 = colg & 15;
    const int kb2 = k >> 5, grp2 = (k >> 3) & 3, e2 = k & 7;
    dst[((size_t)(cb2 * 32 + kb2)) * 4096 + nt2 * 512 + (grp2 * 16 + li2) * 8 +
        e2] = ts[rr][cc];
  }
}

// 64x128 tile dbuf core on fragment-packed operands. Staging: 3 linear
// async16 per thread (A 4KB + B 8KB). All LDS reads lane-linear ->
// conflict-free. Waves split by rows (wave w owns rows w*16..+15).
struct GemmLds64 {
  short As[2][2048];  // 2 x 4 KB
  short Bs[2][4096];  // 2 x 8 KB
};

__device__ inline void gemm_core64f(GemmLds64& lds, const short* __restrict__ Af,
                                    const short* __restrict__ Bf, int nkb,
                                    int rb, int cb, int tid,
                                    f32x4 (&acc)[8]) {
  const int w = tid >> 6, lane = tid & 63;
#pragma unroll
  for (int nt = 0; nt < 8; ++nt) acc[nt] = (f32x4){0.f, 0.f, 0.f, 0.f};

  auto issue = [&](int bi, int kb) {
    const short* a = Af + ((size_t)(rb * nkb + kb)) * 2048;
    const short* b = Bf + ((size_t)(cb * nkb + kb)) * 4096;
    async16(&lds.As[bi][tid * 8], a + tid * 8);
    async16(&lds.Bs[bi][tid * 8], b + tid * 8);
    async16(&lds.Bs[bi][2048 + tid * 8], b + 2048 + tid * 8);
  };

  issue(0, 0);
  for (int kk = 0; kk < nkb; ++kk) {
    const int cur = kk & 1;
    __syncthreads();  // drains only the loads for buffer `cur`
    if (kk + 1 < nkb) issue(cur ^ 1, kk + 1);

    const short8 af = *(const short8*)&lds.As[cur][w * 512 + lane * 8];
    short8 bf[8];
#pragma unroll
    for (int nt = 0; nt < 8; ++nt)
      bf[nt] = *(const short8*)&lds.Bs[cur][nt * 512 + lane * 8];
#pragma unroll
    for (int nt = 0; nt < 8; ++nt)
      acc[nt] = __builtin_amdgcn_mfma_f32_16x16x32_bf16(af, bf[nt], acc[nt],
                                                        0, 0, 0);
  }
}

// Q scale: 1/sqrt(HD) * log2(e) — fattn uses exp2.
#define QSCALE 0.1803368801111f

// Fused QKV projection over concatenated B^T (N=1536), 64x128 tiles.
// K/V bf16 outputs in fattn-fragment order:
//  kbF[b][kh][sb32][ks*2+kg][key32][8]
//  vbF[b][kh][t64][dhalf][kc][kg][d32][8]
__global__ __launch_bounds__(256) void gemm_qkv(
    const short* __restrict__ A, const short* __restrict__ Bt,
    const float* __restrict__ cs, const float* __restrict__ sn,
    short* __restrict__ qb, float* __restrict__ koutp, short* __restrict__ kb,
    float* __restrict__ voutp, short* __restrict__ vbT) {
  __shared__ GemmLds64 lds;
  const int tid = threadIdx.x;
  const int w = tid >> 6, lane = tid & 63;
  const int grp = lane >> 4, li = lane & 15;
  const int rb = blockIdx.y, cb = blockIdx.x;
  const int row0 = rb * 64, col0 = cb * 128;
  f32x4 acc[8];
  gemm_core64f(lds, A, Bt, 32, rb, cb, tid, acc);

  if (col0 < 1024) {  // Q: RoPE + QSCALE (two heads per tile)
#pragma unroll
    for (int h2 = 0; h2 < 2; ++h2)
#pragma unroll
      for (int p = 0; p < 2; ++p) {
        const int nt = h2 * 4 + p;
#pragma unroll
        for (int r = 0; r < 4; ++r) {
          const int row = row0 + w * 16 + grp * 4 + r;
          const int spos = row & (S_ - 1);
          const int col = col0 + nt * 16 + li;
          const int d = p * 16 + li;  // head-dim in [0,32)
          const float c = cs[spos * 32 + d];
          const float s = sn[spos * 32 + d];
          const float x0 = acc[nt][r], x1 = acc[nt + 2][r];
          qb[(size_t)row * 1024 + col] = f2b((x0 * c - x1 * s) * QSCALE);
          qb[(size_t)row * 1024 + col + 32] = f2b((x1 * c + x0 * s) * QSCALE);
        }
      }
  } else if (col0 < 1280) {  // K: RoPE, f32 natural + bf16 fragment-packed
#pragma unroll
    for (int h2 = 0; h2 < 2; ++h2)
#pragma unroll
      for (int p = 0; p < 2; ++p) {
        const int nt = h2 * 4 + p;
#pragma unroll
        for (int r = 0; r < 4; ++r) {
          const int row = row0 + w * 16 + grp * 4 + r;
          const int bq = row >> 11, spos = row & (S_ - 1);
          const int sb = spos >> 5, k32 = spos & 31;
          const int kcol = col0 + nt * 16 + li - 1024;
          const int khk = kcol >> 6, d = kcol & 63;  // d in [0,32)
          const float c = cs[spos * 32 + d];
          const float s = sn[spos * 32 + d];
          const float x0 = acc[nt][r], x1 = acc[nt + 2][r];
          const float k0v = x0 * c - x1 * s;
          const float k1v = x1 * c + x0 * s;
          koutp[(size_t)row * 256 + kcol] = k0v;
          koutp[(size_t)row * 256 + kcol + 32] = k1v;
          short* kbase =
              kb + (((size_t)(bq * 4 + khk) * 64 + sb) * 2048) + k32 * 8;
          const int d2 = d + 32;
          kbase[((d >> 4) * 2 + ((d >> 3) & 1)) * 256 + (d & 7)] = f2b(k0v);
          kbase[((d2 >> 4) * 2 + ((d2 >> 3) & 1)) * 256 + (d2 & 7)] = f2b(k1v);
        }
      }
  } else {  // V: f32 natural + bf16 fragment-packed
#pragma unroll
    for (int nt = 0; nt < 8; ++nt) {
      const int vcol = col0 + nt * 16 + li - 1280;
      const int row_base = row0 + w * 16 + grp * 4;
      short4 pk;
      float vv[4];
#pragma unroll
      for (int r = 0; r < 4; ++r) vv[r] = acc[nt][r];
      pk.x = f2b(vv[0]); pk.y = f2b(vv[1]);
      pk.z = f2b(vv[2]); pk.w = f2b(vv[3]);
#pragma unroll
      for (int r = 0; r < 4; ++r)
        voutp[(size_t)(row_base + r) * 256 + vcol] = vv[r];
      const int bq = row_base >> 11, s0 = row_base & (S_ - 1);
      const int t = s0 >> 6, k64 = s0 & 63;
      const int kc = k64 >> 4, kg8 = (k64 >> 3) & 1, k8 = k64 & 7;
      const int khv = vcol >> 6, d = vcol & 63;
      short* vb = vbT + (((size_t)(bq * 4 + khv) * 32 + t) * 4096) +
                  (d >> 5) * 2048 + kc * 512 + kg8 * 256 + (d & 31) * 8 + k8;
      *(short4*)vb = pk;
    }
  }
}

// Flash attention v13: v9's body + TRIANGULAR PASS-PAIRING (R0's pattern,
// dropped in v6 without recognizing it was load-balancing). R10/R11 showed
// 2048 uniform-resident blocks with 1:32 work spread -> small blocks drain
// instantly, longest blocks finish nearly alone (Occupancy avg 17.8% vs
// 50% resident; MfmaUtil 14%). Pairing q-tile pr with 63-pr makes every
// block exactly ~33 visits -> flat occupancy, no serial tail. Grid 1024.
__global__ __launch_bounds__(128) void fattn_kernel(
    const short* __restrict__ qb, const short* __restrict__ kb,
    const short* __restrict__ vbT, short* __restrict__ o) {
  __shared__ float scr[64 * 33 + 32];  // [d][q] pad-33 transpose + l tail

  const int tid = threadIdx.x;
  const int par = tid >> 6, lane = tid & 63;
  const int n32 = lane & 31, kg = lane >> 5;

  const int pr = blockIdx.x >> 5;  // [0,32): pair {pr, 63-pr}
  const int bh = blockIdx.x & 31;
  const int b = bh >> 4, h = bh & 15, kh = h >> 2;  // GQA n_rep=4

  // Fragment-packed K/V bases: per-(b,kh) stride 131072 shorts (256KB).
  const short* kF = kb + ((size_t)(b * 4 + kh) << 17) + lane * 8;
  const short* vF = vbT + ((size_t)(b * 4 + kh) << 17) + lane * 8;

  f32x16 zero16;
#pragma unroll
  for (int i = 0; i < 16; ++i) zero16[i] = 0.f;

  auto loadK = [&](int t, short8 (&kr)[8]) {
    const short* kt = kF + (size_t)t * 4096;
#pragma unroll
    for (int s = 0; s < 2; ++s)
#pragma unroll
      for (int ks = 0; ks < 4; ++ks)
        kr[s * 4 + ks] = *(const short8*)(kt + s * 2048 + ks * 512);
  };
  auto loadV = [&](int t, short8 (&vr)[8]) {
    const short* vt = vF + (size_t)t * 4096;
#pragma unroll
    for (int kc = 0; kc < 4; ++kc) {
      vr[kc] = *(const short8*)(vt + kc * 512);
      vr[kc + 4] = *(const short8*)(vt + 2048 + kc * 512);
    }
  };

  for (int pass = 0; pass < 2; ++pass) {
    const int qt = pass ? (63 - pr) : pr;  // 32-query tile index [0,64)
    const int qq = qt >> 1, st = qt & 1;   // diag 64-key tile / subtile
    const int nt = qq + 1;                 // # key tiles of 64

    // Q fragment: rows qt*32+n32, dims kg*8 + ks*16 + e.
    const short* qp =
        qb + ((size_t)(b * S_ + qt * 32 + n32)) * 1024 + h * 64 + kg * 8;
    short8 qa[4];
#pragma unroll
    for (int ks = 0; ks < 4; ++ks) qa[ks] = *(const short8*)(qp + ks * 16);

    f32x16 Oa0 = zero16, Oa1 = zero16;
    float lreg = 0.f;

    // Compute on fully-resident registers.
    auto body = [&](int t, const short8 (&kr)[8], const short8 (&vr)[8]) {
      const bool diag = (t == qq);
      unsigned pk[4][4];
#pragma unroll
      for (int s = 0; s < 2; ++s) {
        if (s == 1 && diag && st == 0) continue;  // fully masked subtile
        __builtin_amdgcn_s_setprio(1);
        f32x16 sv = __builtin_amdgcn_mfma_f32_32x32x16_bf16(
            kr[s * 4 + 0], qa[0], zero16, 0, 0, 0);
        sv = __builtin_amdgcn_mfma_f32_32x32x16_bf16(kr[s * 4 + 1], qa[1], sv,
                                                     0, 0, 0);
        sv = __builtin_amdgcn_mfma_f32_32x32x16_bf16(kr[s * 4 + 2], qa[2], sv,
                                                     0, 0, 0);
        sv = __builtin_amdgcn_mfma_f32_32x32x16_bf16(kr[s * 4 + 3], qa[3], sv,
                                                     0, 0, 0);
        __builtin_amdgcn_s_setprio(0);
        const bool dm = diag && (s == st);  // partial-masked subtile
        float e[16];
#pragma unroll
        for (int rr = 0; rr < 16; ++rr) {
          float v = __builtin_amdgcn_exp2f(sv[rr]);
          if (dm) {
            const int key32 = (rr & 3) + 8 * (rr >> 2) + 4 * kg;
            if (key32 > n32) v = 0.f;
          }
          e[rr] = v;
        }
        pk[2 * s][0] = pkbf2(e[0], e[1]);
        pk[2 * s][1] = pkbf2(e[2], e[3]);
        pk[2 * s][2] = pkbf2(e[4], e[5]);
        pk[2 * s][3] = pkbf2(e[6], e[7]);
        pk[2 * s + 1][0] = pkbf2(e[8], e[9]);
        pk[2 * s + 1][1] = pkbf2(e[10], e[11]);
        pk[2 * s + 1][2] = pkbf2(e[12], e[13]);
        pk[2 * s + 1][3] = pkbf2(e[14], e[15]);
        lreg += (((e[0] + e[1]) + (e[2] + e[3])) +
                 ((e[4] + e[5]) + (e[6] + e[7]))) +
                (((e[8] + e[9]) + (e[10] + e[11])) +
                 ((e[12] + e[13]) + (e[14] + e[15])));
      }

      auto pv = [&](int kc) {
        // B fragment: lanes<32 need {own p01,p23 | other-half p45,p67},
        // lanes>=32 the mirror — one permlane32_swap per reg pair.
        auto r02 = __builtin_amdgcn_permlane32_swap(pk[kc][0], pk[kc][2],
                                                    false, false);
        auto r13 = __builtin_amdgcn_permlane32_swap(pk[kc][1], pk[kc][3],
                                                    false, false);
        union { unsigned u[4]; short8 s8; } f;
        f.u[0] = r02[0]; f.u[1] = r13[0]; f.u[2] = r02[1]; f.u[3] = r13[1];
        Oa0 = __builtin_amdgcn_mfma_f32_32x32x16_bf16(vr[kc], f.s8, Oa0, 0, 0,
                                                      0);
        Oa1 = __builtin_amdgcn_mfma_f32_32x32x16_bf16(vr[kc + 4], f.s8, Oa1, 0,
                                                      0, 0);
      };
      __builtin_amdgcn_s_setprio(1);
      if (diag && st == 0) {
        pv(0); pv(1);
      } else {
        pv(0); pv(1); pv(2); pv(3);
      }
      __builtin_amdgcn_s_setprio(0);
    };

    // Software-pipelined main loop: K and V ping-pong, one visit ahead.
    {
      short8 kA[8], kB[8], vA[8], vB[8];
      int t = par;
      if (t < nt) {
        loadK(t, kA);
        loadV(t, vA);
        for (;;) {
          if (t + 2 < nt) { loadV(t + 2, vB); loadK(t + 2, kB); }
          body(t, kA, vA);
          t += 2;
          if (t >= nt) break;
          if (t + 2 < nt) { loadV(t + 2, vA); loadK(t + 2, kA); }
          body(t, kB, vB);
          t += 2;
          if (t >= nt) break;
        }
      }
    }

    // Combine kg halves of l (same q, disjoint keys).
    lreg += __shfl_xor(lreg, 32);

    // Cross-parity combine + normalize + coalesced write via LDS scratch.
    float* lb = scr + 64 * 33;
    if (par == 1) {
#pragma unroll
      for (int rr = 0; rr < 16; ++rr) {
        const int d0 = (rr & 3) + 8 * (rr >> 2) + 4 * kg;
        scr[d0 * 33 + n32] = Oa0[rr];
        scr[(d0 + 32) * 33 + n32] = Oa1[rr];
      }
      if (kg == 0) lb[n32] = lreg;
    }
    __syncthreads();
    if (par == 0) {
      const float inv = __builtin_amdgcn_rcpf(lreg + lb[n32]);
#pragma unroll
      for (int rr = 0; rr < 16; ++rr) {
        const int d0 = (rr & 3) + 8 * (rr >> 2) + 4 * kg;
        scr[d0 * 33 + n32] = (Oa0[rr] + scr[d0 * 33 + n32]) * inv;
        scr[(d0 + 32) * 33 + n32] =
            (Oa1[rr] + scr[(d0 + 32) * 33 + n32]) * inv;
      }
    }
    __syncthreads();
    {
      // Output write -> fragment-packed abufF (A-operand layout for oproj).
      const int q = tid >> 2, seg = (tid & 3) * 16;
      const int row = b * S_ + qt * 32 + q;
      const int rb = row >> 6, w16 = (row >> 4) & 3, li = row & 15;
      short8 t0, t1;
#pragma unroll
      for (int k2 = 0; k2 < 8; ++k2) {
        t0[k2] = f2b(scr[(seg + k2) * 33 + q]);
        t1[k2] = f2b(scr[(seg + 8 + k2) * 33 + q]);
      }
      const int c0 = h * 64 + seg, c1 = c0 + 8;
      *(short8*)(o + ((size_t)(rb * 32 + (c0 >> 5))) * 2048 + w16 * 512 +
                 (((c0 >> 3) & 3) * 16 + li) * 8) = t0;
      *(short8*)(o + ((size_t)(rb * 32 + (c1 >> 5))) * 2048 + w16 * 512 +
                 (((c1 >> 3) & 3) * 16 + li) * 8) = t1;
    }
    __syncthreads();  // scr reuse across passes
  }
}

// O-projection: 64x128 tiles, fragment-packed dbuf core, f32 output.
__global__ __launch_bounds__(256) void gemm_bt_f32(
    const short* __restrict__ A, const short* __restrict__ Bt,
    float* __restrict__ C, int N, int nkb) {
  __shared__ GemmLds64 lds;
  const int tid = threadIdx.x;
  const int w = tid >> 6, lane = tid & 63;
  const int grp = lane >> 4, li = lane & 15;
  const int rb = blockIdx.y, cb = blockIdx.x;
  f32x4 acc[8];
  gemm_core64f(lds, A, Bt, nkb, rb, cb, tid, acc);
  const int row0 = rb * 64, col0 = cb * 128;
#pragma unroll
  for (int nt = 0; nt < 8; ++nt)
#pragma unroll
    for (int r = 0; r < 4; ++r)
      C[(size_t)(row0 + w * 16 + grp * 4 + r) * N + col0 + nt * 16 + li] =
          acc[nt][r];
}

extern "C" void kernel_launch(void* const* d_in, const int* in_sizes, int n_in,
                              void* d_out, int out_size, void* d_ws,
                              size_t ws_size, hipStream_t stream) {
  const float* x  = (const float*)d_in[0];
  const float* cs = (const float*)d_in[1];
  const float* sn = (const float*)d_in[2];
  // d_in[3] = mask (causal, analytic)
  const float* wq = (const float*)d_in[4];
  const float* wk = (const float*)d_in[5];
  const float* wv = (const float*)d_in[6];
  const float* wo = (const float*)d_in[7];

  float* outp  = (float*)d_out;
  float* koutp = outp + (size_t)B_ * S_ * H_ * HD_;     // new_k (f32)
  float* voutp = koutp + (size_t)B_ * S_ * KVH_ * HD_;  // new_v (f32)

  char* p = (char*)d_ws;
  short* xb   = (short*)p; p += (size_t)B_ * S_ * D_ * 2;          // 8 MB
  short* qb   = (short*)p; p += (size_t)B_ * S_ * H_ * HD_ * 2;    // 8 MB
  short* kb   = (short*)p; p += (size_t)B_ * S_ * KVH_ * HD_ * 2;  // 2 MB
  short* vbT  = (short*)p; p += (size_t)B_ * S_ * KVH_ * HD_ * 2;  // 2 MB
  short* abuf = (short*)p; p += (size_t)B_ * S_ * H_ * HD_ * 2;    // 8 MB
  short* wt   = (short*)p; p += (size_t)1536 * D_ * 2;             // 3 MB
  short* wot  = (short*)p; p += (size_t)D_ * H_ * HD_ * 2;         // 2 MB

  const int M = B_ * S_;  // 4096

  // Prepass: fragment-packed bf16 cast + weight transposes.
  prep_kernel<<<4096 + 1024, 256, 0, stream>>>(x, xb, wq, wk, wv, wo, wt,
                                               wot);

  // Fused QKV projection (conflict-free fragment core, 12x64 grid).
  gemm_qkv<<<dim3(12, M / 64), 256, 0, stream>>>(
      xb, wt, cs, sn, qb, koutp, kb, voutp, vbT);

  // Flash attention v13: 1024 pair-balanced blocks, barrier-free core.
  fattn_kernel<<<32 * 32, 128, 0, stream>>>(qb, kb, vbT, abuf);

  // Output projection (conflict-free fragment core, 8x64 grid).
  gemm_bt_f32<<<dim3(8, M / 64), 256, 0, stream>>>(abuf, wot, outp, 1024, 32);
}

// Round 13
// 171.889 us; speedup vs baseline: 1.0793x; 1.0793x over previous
//
#include <hip/hip_runtime.h>
#include <hip/hip_bf16.h>

// Problem constants (f32 in / f32 out — established R1/R2).
constexpr int B_ = 2, S_ = 2048, D_ = 1024, H_ = 16, KVH_ = 4, HD_ = 64;

typedef __attribute__((ext_vector_type(8))) short short8;
typedef __attribute__((ext_vector_type(4))) float f32x4;
typedef __attribute__((ext_vector_type(16))) float f32x16;

// f32 -> bf16 bits, round-to-nearest-even (finite inputs).
__device__ inline short f2b(float x) {
  unsigned u = __float_as_uint(x);
  return (short)((u + 0x7fffu + ((u >> 16) & 1u)) >> 16);
}
// pack two f32 -> (bf16,bf16) u32, lo in low half (v_cvt_pk_bf16_f32).
__device__ inline unsigned pkbf2(float lo, float hi) {
  __hip_bfloat162 h = __float22bfloat162_rn(float2{lo, hi});
  return *(unsigned*)&h;
}

// Async global->LDS, 16B per lane. LDS dest = wave-uniform base + lane*16.
__device__ inline void async16(void* lds, const void* g) {
  __builtin_amdgcn_global_load_lds(
      (const __attribute__((address_space(1))) unsigned int*)g,
      (__attribute__((address_space(3))) unsigned int*)lds, 16, 0, 0);
}

// Merged prepass: blocks [0,4096) cast x f32->bf16; [4096,5120) transpose
// weights (z: 0=wq, 1=wo, 2=wk, 3=wv; W [1024][N] f32 -> bf16 [N][1024]).
__global__ __launch_bounds__(256) void prep_kernel(
    const float* __restrict__ x, short* __restrict__ xb,
    const float* __restrict__ wq, const float* __restrict__ wk,
    const float* __restrict__ wv, const float* __restrict__ wo,
    short* __restrict__ wt, short* __restrict__ wot) {
  __shared__ short ts[64][66];
  const int tid = threadIdx.x;
  if (blockIdx.x < 4096) {
    const int idx = (blockIdx.x * 256 + tid) * 4;
    float4 v = *(const float4*)(x + idx);
    short4 o;
    o.x = f2b(v.x); o.y = f2b(v.y); o.z = f2b(v.z); o.w = f2b(v.w);
    *(short4*)(xb + idx) = o;
    return;
  }
  const int bid = blockIdx.x - 4096;
  const int z = bid >> 8, bi = (bid >> 4) & 15, bj = bid & 15;
  const float* W;
  short* dst;
  int N;
  if (z == 0)      { W = wq; dst = wt;                       N = 1024; }
  else if (z == 1) { W = wo; dst = wot;                      N = 1024; }
  else if (z == 2) { W = wk; dst = wt + (size_t)1024 * 1024; N = 256; }
  else             { W = wv; dst = wt + (size_t)1280 * 1024; N = 256; }
  if (bj * 64 >= N) return;
#pragma unroll
  for (int i = 0; i < 16; ++i) {
    int idx = tid + i * 256;
    int r = idx >> 6, c = idx & 63;
    ts[r][c] = f2b(W[(size_t)(bi * 64 + r) * N + bj * 64 + c]);
  }
  __syncthreads();
#pragma unroll
  for (int i = 0; i < 16; ++i) {
    int idx = tid + i * 256;
    int cc = idx >> 6, rr = idx & 63;
    dst[(size_t)(bj * 64 + cc) * 1024 + bi * 64 + rr] = ts[rr][cc];
  }
}

// Double-buffered single-barrier MFMA GEMM core (issue-after-barrier): one
// __syncthreads per K-iter; loads for iter k+1 in flight during compute of
// iter k. 128x128 tile, BK=32.
struct GemmLdsDb {
  short As[2][128][32];
  short Bs[2][128][32];
};

__device__ inline void gemm_core_db(GemmLdsDb& lds, const short* __restrict__ A,
                                    const short* __restrict__ Bt, int K,
                                    int row0, int col0, int tid,
                                    f32x4 (&acc)[4][4]) {
  const int w = tid >> 6, lane = tid & 63;
  const int grp = lane >> 4, li = lane & 15;
  const int wr = w & 1, wc = w >> 1;
  const int lr = lane >> 2, ls = (lane & 3) * 8;
#pragma unroll
  for (int mt = 0; mt < 4; ++mt)
#pragma unroll
    for (int nt = 0; nt < 4; ++nt) acc[mt][nt] = (f32x4){0.f, 0.f, 0.f, 0.f};

  auto issue = [&](int bi, int k0) {
#pragma unroll
    for (int i = 0; i < 2; ++i) {
      const int r = i * 64 + w * 16;
      async16(&lds.As[bi][r][0], A + (size_t)(row0 + r + lr) * K + k0 + ls);
      async16(&lds.Bs[bi][r][0], Bt + (size_t)(col0 + r + lr) * K + k0 + ls);
    }
  };

  issue(0, 0);
  const int nk = K >> 5;
  for (int kk = 0; kk < nk; ++kk) {
    const int cur = kk & 1;
    __syncthreads();  // drains only the loads for buffer `cur`
    if (kk + 1 < nk) issue(cur ^ 1, (kk + 1) << 5);

    short8 af[4], bf[4];
#pragma unroll
    for (int mt = 0; mt < 4; ++mt)
      af[mt] = *(const short8*)&lds.As[cur][wr * 64 + mt * 16 + li][grp * 8];
#pragma unroll
    for (int nt = 0; nt < 4; ++nt)
      bf[nt] = *(const short8*)&lds.Bs[cur][wc * 64 + nt * 16 + li][grp * 8];
#pragma unroll
    for (int mt = 0; mt < 4; ++mt)
#pragma unroll
      for (int nt = 0; nt < 4; ++nt)
        acc[mt][nt] = __builtin_amdgcn_mfma_f32_16x16x32_bf16(
            af[mt], bf[nt], acc[mt][nt], 0, 0, 0);
  }
}

// Q scale: 1/sqrt(HD) * log2(e) — fattn uses exp2.
#define QSCALE 0.1803368801111f

// Fused QKV projection over concatenated B^T (N=1536).
// K/V bf16 outputs are written in MFMA-FRAGMENT order:
//  kbF[b][kh][sb32][ks*2+kg][key32][8]  (2048 shorts per 32-key block)
//  vbF[b][kh][t64][dhalf][kc][kg][d32][8] (4096 shorts per 64-key tile)
// so fattn's fragment loads are base + lane*16B contiguous (1KB/wave-load).
__global__ __launch_bounds__(256) void gemm_qkv(
    const short* __restrict__ A, const short* __restrict__ Bt,
    const float* __restrict__ cs, const float* __restrict__ sn,
    short* __restrict__ qb, float* __restrict__ koutp, short* __restrict__ kb,
    float* __restrict__ voutp, short* __restrict__ vbT) {
  __shared__ GemmLdsDb lds;
  const int tid = threadIdx.x;
  const int w = tid >> 6, lane = tid & 63;
  const int grp = lane >> 4, li = lane & 15;
  const int wr = w & 1, wc = w >> 1;
  const int row0 = blockIdx.y * 128, col0 = blockIdx.x * 128;
  f32x4 acc[4][4];
  gemm_core_db(lds, A, Bt, D_, row0, col0, tid, acc);

  if (col0 < 1024) {  // Q: RoPE + QSCALE
#pragma unroll
    for (int mt = 0; mt < 4; ++mt)
#pragma unroll
      for (int r = 0; r < 4; ++r) {
        const int row = row0 + wr * 64 + mt * 16 + grp * 4 + r;
        const int spos = row & (S_ - 1);
#pragma unroll
        for (int nt = 0; nt < 2; ++nt) {
          const int col = col0 + wc * 64 + nt * 16 + li;
          const int d = col & 63;
          const float c = cs[spos * 32 + d];
          const float s = sn[spos * 32 + d];
          const float x0 = acc[mt][nt][r], x1 = acc[mt][nt + 2][r];
          qb[(size_t)row * 1024 + col] = f2b((x0 * c - x1 * s) * QSCALE);
          qb[(size_t)row * 1024 + col + 32] = f2b((x1 * c + x0 * s) * QSCALE);
        }
      }
  } else if (col0 < 1280) {  // K: RoPE, f32 natural + bf16 fragment-packed
#pragma unroll
    for (int mt = 0; mt < 4; ++mt)
#pragma unroll
      for (int r = 0; r < 4; ++r) {
        const int row = row0 + wr * 64 + mt * 16 + grp * 4 + r;
        const int bq = row >> 11, spos = row & (S_ - 1);
        const int sb = spos >> 5, k32 = spos & 31;
#pragma unroll
        for (int nt = 0; nt < 2; ++nt) {
          const int kcol = col0 + wc * 64 + nt * 16 + li - 1024;
          const int khk = kcol >> 6, d = kcol & 63;  // d in [0,32)
          const float c = cs[spos * 32 + d];
          const float s = sn[spos * 32 + d];
          const float x0 = acc[mt][nt][r], x1 = acc[mt][nt + 2][r];
          const float k0v = x0 * c - x1 * s;
          const float k1v = x1 * c + x0 * s;
          koutp[(size_t)row * 256 + kcol] = k0v;
          koutp[(size_t)row * 256 + kcol + 32] = k1v;
          short* kbase =
              kb + (((size_t)(bq * 4 + khk) * 64 + sb) * 2048) + k32 * 8;
          const int d2 = d + 32;
          kbase[((d >> 4) * 2 + ((d >> 3) & 1)) * 256 + (d & 7)] = f2b(k0v);
          kbase[((d2 >> 4) * 2 + ((d2 >> 3) & 1)) * 256 + (d2 & 7)] = f2b(k1v);
        }
      }
  } else {  // V: f32 natural + bf16 fragment-packed
#pragma unroll
    for (int mt = 0; mt < 4; ++mt)
#pragma unroll
      for (int nt = 0; nt < 4; ++nt) {
        const int vcol = col0 + wc * 64 + nt * 16 + li - 1280;
        const int row_base = row0 + wr * 64 + mt * 16 + grp * 4;
        short4 pk;
        float vv[4];
#pragma unroll
        for (int r = 0; r < 4; ++r) vv[r] = acc[mt][nt][r];
        pk.x = f2b(vv[0]); pk.y = f2b(vv[1]);
        pk.z = f2b(vv[2]); pk.w = f2b(vv[3]);
#pragma unroll
        for (int r = 0; r < 4; ++r)
          voutp[(size_t)(row_base + r) * 256 + vcol] = vv[r];
        const int bq = row_base >> 11, s0 = row_base & (S_ - 1);
        const int t = s0 >> 6, k64 = s0 & 63;
        const int kc = k64 >> 4, kg8 = (k64 >> 3) & 1, k8 = k64 & 7;
        const int khv = vcol >> 6, d = vcol & 63;
        short* vb = vbT + (((size_t)(bq * 4 + khv) * 32 + t) * 4096) +
                    (d >> 5) * 2048 + kc * 512 + kg8 * 256 + (d & 31) * 8 + k8;
        *(short4*)vb = pk;
      }
  }
}

// Flash attention v8: barrier-free + register pipeline + COALESCED loads.
// K/V stored fragment-packed by the QKV epilogue, so every fragment load
// here is base + lane*16B (1KB contiguous). V(t) loads issue BEFORE K(t+2)
// prefetch so the PV vmcnt wait doesn't drain the prefetch (FIFO order).
__global__ __launch_bounds__(128) void fattn_kernel(
    const short* __restrict__ qb, const short* __restrict__ kb,
    const short* __restrict__ vbT, short* __restrict__ o) {
  __shared__ float scr[64 * 33 + 32];  // [d][q] pad-33 transpose + l tail

  const int tid = threadIdx.x;
  const int par = tid >> 6, lane = tid & 63;
  const int n32 = lane & 31, kg = lane >> 5;

  // Descending work order: big blocks dispatch first.
  const int qt = 63 - (blockIdx.x >> 5);  // 32-query tile index [0,64)
  const int bh = blockIdx.x & 31;
  const int b = bh >> 4, h = bh & 15, kh = h >> 2;  // GQA n_rep=4
  const int qq = qt >> 1, st = qt & 1;  // diag 64-key tile / subtile
  const int nt = qq + 1;                // # key tiles of 64

  // Q fragment: rows qt*32+n32, dims kg*8 + ks*16 + e.
  const short* qp =
      qb + ((size_t)(b * S_ + qt * 32 + n32)) * 1024 + h * 64 + kg * 8;
  short8 qa[4];
#pragma unroll
  for (int ks = 0; ks < 4; ++ks) qa[ks] = *(const short8*)(qp + ks * 16);

  // Fragment-packed K/V bases: per-(b,kh) stride 131072 shorts (256KB).
  const short* kF = kb + ((size_t)(b * 4 + kh) << 17) + lane * 8;
  const short* vF = vbT + ((size_t)(b * 4 + kh) << 17) + lane * 8;

  f32x16 zero16;
#pragma unroll
  for (int i = 0; i < 16; ++i) zero16[i] = 0.f;
  f32x16 Oa0 = zero16, Oa1 = zero16;
  float lreg = 0.f;

  // K fragment loader: full 64-key tile t — 8 contiguous 1KB wave-loads.
  auto loadK = [&](int t, short8 (&kr)[8]) {
    const short* kt = kF + (size_t)t * 4096;
#pragma unroll
    for (int s = 0; s < 2; ++s)
#pragma unroll
      for (int ks = 0; ks < 4; ++ks)
        kr[s * 4 + ks] = *(const short8*)(kt + s * 2048 + ks * 512);
  };

  // Tile body: V loads first, then K(t+2) prefetch, then compute on
  // resident kr registers.
  auto body = [&](int t, const short8 (&kr)[8], short8 (&knx)[8]) {
    const bool diag = (t == qq);
    const short* vt = vF + (size_t)t * 4096;
    short8 vr[8];
#pragma unroll
    for (int kc = 0; kc < 4; ++kc) {
      vr[kc] = *(const short8*)(vt + kc * 512);
      vr[kc + 4] = *(const short8*)(vt + 2048 + kc * 512);
    }
    if (t + 2 < nt) loadK(t + 2, knx);  // wave-uniform branch

    unsigned pk[4][4];
#pragma unroll
    for (int s = 0; s < 2; ++s) {
      if (s == 1 && diag && st == 0) continue;  // fully masked subtile
      f32x16 sv = __builtin_amdgcn_mfma_f32_32x32x16_bf16(kr[s * 4 + 0], qa[0],
                                                          zero16, 0, 0, 0);
      sv = __builtin_amdgcn_mfma_f32_32x32x16_bf16(kr[s * 4 + 1], qa[1], sv, 0,
                                                   0, 0);
      sv = __builtin_amdgcn_mfma_f32_32x32x16_bf16(kr[s * 4 + 2], qa[2], sv, 0,
                                                   0, 0);
      sv = __builtin_amdgcn_mfma_f32_32x32x16_bf16(kr[s * 4 + 3], qa[3], sv, 0,
                                                   0, 0);
      const bool dm = diag && (s == st);  // partial-masked subtile
      float e[16];
#pragma unroll
      for (int rr = 0; rr < 16; ++rr) {
        float v = __builtin_amdgcn_exp2f(sv[rr]);
        if (dm) {
          const int key32 = (rr & 3) + 8 * (rr >> 2) + 4 * kg;
          if (key32 > n32) v = 0.f;
        }
        e[rr] = v;
      }
      pk[2 * s][0] = pkbf2(e[0], e[1]);
      pk[2 * s][1] = pkbf2(e[2], e[3]);
      pk[2 * s][2] = pkbf2(e[4], e[5]);
      pk[2 * s][3] = pkbf2(e[6], e[7]);
      pk[2 * s + 1][0] = pkbf2(e[8], e[9]);
      pk[2 * s + 1][1] = pkbf2(e[10], e[11]);
      pk[2 * s + 1][2] = pkbf2(e[12], e[13]);
      pk[2 * s + 1][3] = pkbf2(e[14], e[15]);
      lreg += (((e[0] + e[1]) + (e[2] + e[3])) +
               ((e[4] + e[5]) + (e[6] + e[7]))) +
              (((e[8] + e[9]) + (e[10] + e[11])) +
               ((e[12] + e[13]) + (e[14] + e[15])));
    }

    auto pv = [&](int kc) {
      // Build B fragment: lanes<32 need {own p01,p23 | other-half p45,p67},
      // lanes>=32 the mirror — one permlane32_swap per reg pair.
      auto r02 =
          __builtin_amdgcn_permlane32_swap(pk[kc][0], pk[kc][2], false, false);
      auto r13 =
          __builtin_amdgcn_permlane32_swap(pk[kc][1], pk[kc][3], false, false);
      union { unsigned u[4]; short8 s8; } f;
      f.u[0] = r02[0]; f.u[1] = r13[0]; f.u[2] = r02[1]; f.u[3] = r13[1];
      Oa0 = __builtin_amdgcn_mfma_f32_32x32x16_bf16(vr[kc], f.s8, Oa0, 0, 0, 0);
      Oa1 = __builtin_amdgcn_mfma_f32_32x32x16_bf16(vr[kc + 4], f.s8, Oa1, 0,
                                                    0, 0);
    };
    if (diag && st == 0) {
      pv(0); pv(1);
    } else {
      pv(0); pv(1); pv(2); pv(3);
    }
  };

  // Software-pipelined main loop: ping-pong K register buffers.
  {
    short8 kA[8], kB[8];
    int t = par;
    if (t < nt) {
      loadK(t, kA);
      for (;;) {
        body(t, kA, kB);
        t += 2;
        if (t >= nt) break;
        body(t, kB, kA);
        t += 2;
        if (t >= nt) break;
      }
    }
  }

  // Combine kg halves of l (same q, disjoint keys).
  lreg += __shfl_xor(lreg, 32);

  // Cross-parity combine + normalize + coalesced write via LDS scratch.
  float* lb = scr + 64 * 33;
  if (par == 1) {
#pragma unroll
    for (int rr = 0; rr < 16; ++rr) {
      const int d0 = (rr & 3) + 8 * (rr >> 2) + 4 * kg;
      scr[d0 * 33 + n32] = Oa0[rr];
      scr[(d0 + 32) * 33 + n32] = Oa1[rr];
    }
    if (kg == 0) lb[n32] = lreg;
  }
  __syncthreads();
  if (par == 0) {
    const float inv = __builtin_amdgcn_rcpf(lreg + lb[n32]);
#pragma unroll
    for (int rr = 0; rr < 16; ++rr) {
      const int d0 = (rr & 3) + 8 * (rr >> 2) + 4 * kg;
      scr[d0 * 33 + n32] = (Oa0[rr] + scr[d0 * 33 + n32]) * inv;
      scr[(d0 + 32) * 33 + n32] = (Oa1[rr] + scr[(d0 + 32) * 33 + n32]) * inv;
    }
  }
  __syncthreads();
  {
    const int q = tid >> 2, seg = (tid & 3) * 16;
    const size_t gb = ((size_t)(b * S_ + qt * 32 + q)) * 1024 + h * 64 + seg;
    short8 t0, t1;
#pragma unroll
    for (int k2 = 0; k2 < 8; ++k2) {
      t0[k2] = f2b(scr[(seg + k2) * 33 + q]);
      t1[k2] = f2b(scr[(seg + 8 + k2) * 33 + q]);
    }
    *(short8*)(o + gb) = t0;
    *(short8*)(o + gb + 8) = t1;
  }
}

// O-projection: 128x128 tiles, dbuf core, f32 output.
__global__ __launch_bounds__(256) void gemm_bt_f32(
    const short* __restrict__ A, const short* __restrict__ Bt,
    float* __restrict__ C, int N, int K) {
  __shared__ GemmLdsDb lds;
  const int tid = threadIdx.x;
  const int w = tid >> 6, lane = tid & 63;
  const int grp = lane >> 4, li = lane & 15;
  const int wr = w & 1, wc = w >> 1;
  const int row0 = blockIdx.y * 128, col0 = blockIdx.x * 128;
  f32x4 acc[4][4];
  gemm_core_db(lds, A, Bt, K, row0, col0, tid, acc);
#pragma unroll
  for (int mt = 0; mt < 4; ++mt)
#pragma unroll
    for (int nt = 0; nt < 4; ++nt)
#pragma unroll
      for (int r = 0; r < 4; ++r)
        C[(size_t)(row0 + wr * 64 + mt * 16 + grp * 4 + r) * N + col0 +
          wc * 64 + nt * 16 + li] = acc[mt][nt][r];
}

extern "C" void kernel_launch(void* const* d_in, const int* in_sizes, int n_in,
                              void* d_out, int out_size, void* d_ws,
                              size_t ws_size, hipStream_t stream) {
  const float* x  = (const float*)d_in[0];
  const float* cs = (const float*)d_in[1];
  const float* sn = (const float*)d_in[2];
  // d_in[3] = mask (causal, analytic)
  const float* wq = (const float*)d_in[4];
  const float* wk = (const float*)d_in[5];
  const float* wv = (const float*)d_in[6];
  const float* wo = (const float*)d_in[7];

  float* outp  = (float*)d_out;
  float* koutp = outp + (size_t)B_ * S_ * H_ * HD_;     // new_k (f32)
  float* voutp = koutp + (size_t)B_ * S_ * KVH_ * HD_;  // new_v (f32)

  char* p = (char*)d_ws;
  short* xb   = (short*)p; p += (size_t)B_ * S_ * D_ * 2;          // 8 MB
  short* qb   = (short*)p; p += (size_t)B_ * S_ * H_ * HD_ * 2;    // 8 MB
  short* kb   = (short*)p; p += (size_t)B_ * S_ * KVH_ * HD_ * 2;  // 2 MB
  short* vbT  = (short*)p; p += (size_t)B_ * S_ * KVH_ * HD_ * 2;  // 2 MB
  short* abuf = (short*)p; p += (size_t)B_ * S_ * H_ * HD_ * 2;    // 8 MB
  short* wt   = (short*)p; p += (size_t)1536 * D_ * 2;             // 3 MB
  short* wot  = (short*)p; p += (size_t)D_ * H_ * HD_ * 2;         // 2 MB

  const int M = B_ * S_;  // 4096

  // Prepass: bf16 cast + all weight transposes (single launch).
  prep_kernel<<<4096 + 1024, 256, 0, stream>>>(x, xb, wq, wk, wv, wo, wt,
                                               wot);

  // Fused QKV projection (MFMA, dbuf) with RoPE / fragment-pack epilogues.
  gemm_qkv<<<dim3(1536 / 128, M / 128), 256, 0, stream>>>(
      xb, wt, cs, sn, qb, koutp, kb, voutp, vbT);

  // Flash attention v8: 2048 blocks, barrier-free, coalesced fragment loads.
  fattn_kernel<<<64 * 32, 128, 0, stream>>>(qb, kb, vbT, abuf);

  // Output projection (MFMA, dbuf) -> f32 d_out.
  gemm_bt_f32<<<dim3(1024 / 128, M / 128), 256, 0, stream>>>(abuf, wot, outp,
                                                             1024, 1024);
}